// Round 2
// baseline (898.289 us; speedup 1.0000x reference)
//
#include <hip/hip_runtime.h>

#define B 32
#define NW2V 300
#define NR 200

// r_T[j][b] = bias[j] + sum_k q[b][k] * W[k][j]   -> [N_R, B] layout
__global__ void compute_r_kernel(const float* __restrict__ q,
                                 const float* __restrict__ W,
                                 const float* __restrict__ bias,
                                 float* __restrict__ rT) {
    int tid = blockIdx.x * blockDim.x + threadIdx.x;
    if (tid >= NR * B) return;
    int b = tid & (B - 1);
    int j = tid >> 5;
    float acc = bias[j];
    for (int k = 0; k < NW2V; ++k)
        acc += q[b * NW2V + k] * W[k * NR + j];
    rT[j * B + b] = acc;
}

// x [B, N_E] -> xT [N_E, B], LDS-tiled, coalesced both sides
__global__ void transpose_in_kernel(const float* __restrict__ x,
                                    float* __restrict__ xT, int n_e) {
    __shared__ float tile[64][33];
    int e0 = blockIdx.x * 64;
    for (int p = 0; p < 8; ++p) {
        int idx = p * 256 + threadIdx.x;
        int b = idx >> 6, e = idx & 63;              // consecutive tid -> consecutive e
        if (e0 + e < n_e) tile[e][b] = x[(size_t)b * n_e + e0 + e];
    }
    __syncthreads();
    for (int p = 0; p < 8; ++p) {
        int idx = p * 256 + threadIdx.x;
        int b = idx & 31, e = idx >> 5;              // consecutive tid -> consecutive b
        if (e0 + e < n_e) xT[(size_t)(e0 + e) * B + b] = tile[e][b];
    }
}

// xT [N_E, B] -> out [B, N_E]
__global__ void transpose_out_kernel(const float* __restrict__ xT,
                                     float* __restrict__ out, int n_e) {
    __shared__ float tile[64][33];
    int e0 = blockIdx.x * 64;
    for (int p = 0; p < 8; ++p) {
        int idx = p * 256 + threadIdx.x;
        int b = idx & 31, e = idx >> 5;              // coalesced read from xT
        if (e0 + e < n_e) tile[e][b] = xT[(size_t)(e0 + e) * B + b];
    }
    __syncthreads();
    for (int p = 0; p < 8; ++p) {
        int idx = p * 256 + threadIdx.x;
        int b = idx >> 6, e = idx & 63;              // coalesced write to out
        if (e0 + e < n_e) out[(size_t)b * n_e + e0 + e] = tile[e][b];
    }
}

// One follow step in transposed layout. 32 lanes (half-wave) per triple:
// outT[obj[t]][b] += xT[subj[t]][b] * rT[rel[t]][b]
__global__ void hop_kernel(const float* __restrict__ xT,
                           const float* __restrict__ rT,
                           float* __restrict__ outT,
                           const int* __restrict__ subj,
                           const int* __restrict__ rel,
                           const int* __restrict__ obj,
                           const int* __restrict__ n_hop,
                           int hop, int n_t, int n_e) {
    long tid = (long)blockIdx.x * blockDim.x + threadIdx.x;
    if (*n_hop < hop) {                // degenerate: identity pass-through
        long n = (long)n_e * B;
        if (tid < n) outT[tid] = xT[tid];
        return;
    }
    int t = (int)(tid >> 5);
    if (t >= n_t) return;
    int b = (int)(tid & 31);
    int s = subj[t];                   // same addr across half-wave: L1 broadcast
    int r = rel[t];
    int o = obj[t];
    float v = xT[s * B + b] * rT[r * B + b];
    atomicAdd(&outT[o * B + b], v);
}

extern "C" void kernel_launch(void* const* d_in, const int* in_sizes, int n_in,
                              void* d_out, int out_size, void* d_ws, size_t ws_size,
                              hipStream_t stream) {
    const float* x    = (const float*)d_in[0];
    const float* q    = (const float*)d_in[1];
    const int*   subj = (const int*)d_in[2];
    const int*   rel  = (const int*)d_in[3];
    const int*   obj  = (const int*)d_in[4];
    const float* W1   = (const float*)d_in[5];
    const float* bb1  = (const float*)d_in[6];
    const float* W2   = (const float*)d_in[7];
    const float* bb2  = (const float*)d_in[8];
    const float* W3   = (const float*)d_in[9];
    const float* bb3  = (const float*)d_in[10];
    const int*   n_hop = (const int*)d_in[11];
    float* out = (float*)d_out;

    const int n_e = in_sizes[0] / B;   // 500000
    const int n_t = in_sizes[2];       // 2000000

    // Workspace layout: EXACTLY the two big ping-pong buffers (128,000,000 B).
    // rT lives in the head of d_out (64 MB) — it is only read during the hop
    // kernels and d_out is fully overwritten by transpose_out at the end.
    // (Round-1 failure: rT past the 128 MB mark overran ws and corrupted the
    // harness's pristine buffers -> post-timing divergence.)
    float* bufA = (float*)d_ws;                       // [N_E, B]
    float* bufB = bufA + (size_t)n_e * B;             // [N_E, B]
    float* rT   = out;                                 // 3 * [N_R, B] = 75 KB scratch

    const int rblocks = (NR * B + 255) / 256;
    compute_r_kernel<<<rblocks, 256, 0, stream>>>(q, W1, bb1, rT + 0 * NR * B);
    compute_r_kernel<<<rblocks, 256, 0, stream>>>(q, W2, bb2, rT + 1 * NR * B);
    compute_r_kernel<<<rblocks, 256, 0, stream>>>(q, W3, bb3, rT + 2 * NR * B);

    const int tblocks = (n_e + 63) / 64;
    transpose_in_kernel<<<tblocks, 256, 0, stream>>>(x, bufA, n_e);

    const long total   = (long)n_t * 32;
    const int  hblocks = (int)((total + 255) / 256);
    const size_t bytes = (size_t)n_e * B * sizeof(float);

    hipMemsetAsync(bufB, 0, bytes, stream);
    hop_kernel<<<hblocks, 256, 0, stream>>>(bufA, rT + 0 * NR * B, bufB,
                                            subj, rel, obj, n_hop, 1, n_t, n_e);
    hipMemsetAsync(bufA, 0, bytes, stream);
    hop_kernel<<<hblocks, 256, 0, stream>>>(bufB, rT + 1 * NR * B, bufA,
                                            subj, rel, obj, n_hop, 2, n_t, n_e);
    hipMemsetAsync(bufB, 0, bytes, stream);
    hop_kernel<<<hblocks, 256, 0, stream>>>(bufA, rT + 2 * NR * B, bufB,
                                            subj, rel, obj, n_hop, 3, n_t, n_e);

    transpose_out_kernel<<<tblocks, 256, 0, stream>>>(bufB, out, n_e);
}

// Round 3
// 590.302 us; speedup vs baseline: 1.5217x; 1.5217x over previous
//
#include <hip/hip_runtime.h>
#include <hip/hip_fp16.h>

#define B 32
#define NW2V 300
#define NR 200

// r_T[j][b] = bias[j] + sum_k q[b][k] * W[k][j]   -> [N_R, B] layout, fp32
__global__ void compute_r_kernel(const float* __restrict__ q,
                                 const float* __restrict__ W,
                                 const float* __restrict__ bias,
                                 float* __restrict__ rT) {
    int tid = blockIdx.x * blockDim.x + threadIdx.x;
    if (tid >= NR * B) return;
    int b = tid & (B - 1);
    int j = tid >> 5;
    float acc = bias[j];
    for (int k = 0; k < NW2V; ++k)
        acc += q[b * NW2V + k] * W[k * NR + j];
    rT[j * B + b] = acc;
}

// x [B, N_E] f32 -> xT [N_E, B] f16, LDS-tiled, coalesced both sides
__global__ void transpose_in_kernel(const float* __restrict__ x,
                                    __half* __restrict__ xT, int n_e) {
    __shared__ float tile[64][33];
    int e0 = blockIdx.x * 64;
    for (int p = 0; p < 8; ++p) {
        int idx = p * 256 + threadIdx.x;
        int b = idx >> 6, e = idx & 63;              // consecutive tid -> consecutive e
        if (e0 + e < n_e) tile[e][b] = x[(size_t)b * n_e + e0 + e];
    }
    __syncthreads();
    for (int p = 0; p < 8; ++p) {
        int idx = p * 256 + threadIdx.x;
        int b = idx & 31, e = idx >> 5;              // consecutive tid -> consecutive b
        if (e0 + e < n_e) xT[(size_t)(e0 + e) * B + b] = __float2half(tile[e][b]);
    }
}

// xT [N_E, B] f16 -> out [B, N_E] f32
__global__ void transpose_out_kernel(const __half* __restrict__ xT,
                                     float* __restrict__ out, int n_e) {
    __shared__ float tile[64][33];
    int e0 = blockIdx.x * 64;
    for (int p = 0; p < 8; ++p) {
        int idx = p * 256 + threadIdx.x;
        int b = idx & 31, e = idx >> 5;              // coalesced read from xT
        if (e0 + e < n_e) tile[e][b] = __half2float(xT[(size_t)(e0 + e) * B + b]);
    }
    __syncthreads();
    for (int p = 0; p < 8; ++p) {
        int idx = p * 256 + threadIdx.x;
        int b = idx >> 6, e = idx & 63;              // coalesced write to out
        if (e0 + e < n_e) out[(size_t)b * n_e + e0 + e] = tile[e][b];
    }
}

// One follow step, transposed fp16 layout. 16 lanes per triple, each lane
// owns a batch PAIR: outT[obj[t]][2l..2l+1] += xT[subj[t]][...] * rT[rel[t]][...]
// via native packed-f16 atomic (global_atomic_pk_add_f16) — halves atomic
// count AND atomic write bytes vs round-2's 64M f32 atomics.
__global__ void hop_kernel(const __half* __restrict__ xT,
                           const float* __restrict__ rT,
                           __half* __restrict__ outT,
                           const int* __restrict__ subj,
                           const int* __restrict__ rel,
                           const int* __restrict__ obj,
                           const int* __restrict__ n_hop,
                           int hop, int n_t, int n_e) {
    long tid = (long)blockIdx.x * blockDim.x + threadIdx.x;
    if (*n_hop < hop) {                // degenerate: identity pass-through
        long n = (long)n_e * B;
        if (tid < n) outT[tid] = xT[tid];
        return;
    }
    int t = (int)(tid >> 4);
    if (t >= n_t) return;
    int l = (int)(tid & 15);           // batch pair index
    int s = subj[t];
    int r = rel[t];
    int o = obj[t];
    __half2 xh = ((const __half2*)xT)[s * 16 + l];          // 4B gather, 64B/triple
    float2  rf = ((const float2*)rT)[r * 16 + l];           // L1-resident
    float v0 = __half2float(xh.x) * rf.x;
    float v1 = __half2float(xh.y) * rf.y;
    unsafeAtomicAdd(((__half2*)outT) + o * 16 + l, __floats2half2_rn(v0, v1));
}

extern "C" void kernel_launch(void* const* d_in, const int* in_sizes, int n_in,
                              void* d_out, int out_size, void* d_ws, size_t ws_size,
                              hipStream_t stream) {
    const float* x    = (const float*)d_in[0];
    const float* q    = (const float*)d_in[1];
    const int*   subj = (const int*)d_in[2];
    const int*   rel  = (const int*)d_in[3];
    const int*   obj  = (const int*)d_in[4];
    const float* W1   = (const float*)d_in[5];
    const float* bb1  = (const float*)d_in[6];
    const float* W2   = (const float*)d_in[7];
    const float* bb2  = (const float*)d_in[8];
    const float* W3   = (const float*)d_in[9];
    const float* bb3  = (const float*)d_in[10];
    const int*   n_hop = (const int*)d_in[11];
    float* out = (float*)d_out;

    const int n_e = in_sizes[0] / B;   // 500000
    const int n_t = in_sizes[2];       // 2000000

    // ws layout (fits 128 MB): two f16 ping-pong buffers (32 MB each) + rT (75 KB)
    __half* bufA = (__half*)d_ws;                      // [N_E, B] f16
    __half* bufB = bufA + (size_t)n_e * B;             // [N_E, B] f16
    float*  rT   = (float*)(bufB + (size_t)n_e * B);   // 3 * [N_R, B] f32

    const int rblocks = (NR * B + 255) / 256;
    compute_r_kernel<<<rblocks, 256, 0, stream>>>(q, W1, bb1, rT + 0 * NR * B);
    compute_r_kernel<<<rblocks, 256, 0, stream>>>(q, W2, bb2, rT + 1 * NR * B);
    compute_r_kernel<<<rblocks, 256, 0, stream>>>(q, W3, bb3, rT + 2 * NR * B);

    const int tblocks = (n_e + 63) / 64;
    transpose_in_kernel<<<tblocks, 256, 0, stream>>>(x, bufA, n_e);

    const long total   = (long)n_t * 16;
    const int  hblocks = (int)((total + 255) / 256);
    const size_t bytes = (size_t)n_e * B * sizeof(__half);

    hipMemsetAsync(bufB, 0, bytes, stream);
    hop_kernel<<<hblocks, 256, 0, stream>>>(bufA, rT + 0 * NR * B, bufB,
                                            subj, rel, obj, n_hop, 1, n_t, n_e);
    hipMemsetAsync(bufA, 0, bytes, stream);
    hop_kernel<<<hblocks, 256, 0, stream>>>(bufB, rT + 1 * NR * B, bufA,
                                            subj, rel, obj, n_hop, 2, n_t, n_e);
    hipMemsetAsync(bufB, 0, bytes, stream);
    hop_kernel<<<hblocks, 256, 0, stream>>>(bufA, rT + 2 * NR * B, bufB,
                                            subj, rel, obj, n_hop, 3, n_t, n_e);

    transpose_out_kernel<<<tblocks, 256, 0, stream>>>(bufB, out, n_e);
}